// Round 2
// baseline (344.124 us; speedup 1.0000x reference)
//
#include <hip/hip_runtime.h>

// RocketConv: depthwise dilated conv with 84 fixed ternary kernels.
// x: (B=16, C=16, T=4096) fp32 -> out viewed as (B, K=84, C, T) fp32, but the
// underlying buffer is the conv output in (B, C, K, T) row order (the reference
// reshape is a pure view: row r = c*K + k holds conv(channel c, kernel k)).
// y_k[t] = -S[t] + 3*(tap[a]+tap[b]+tap[c]) with S = sum of all 9 taps,
// taps at x[t + 4*j - 16], j=0..8 (zero padded).
// Write-BW bound: 352 MB out / ~6 TB/s ~ 60 us floor.

#define KLEN 9
#define NK   84
#define BB   16
#define CC   16
#define TT   4096
#define TILE 1024
#define HALO 16
#define LDS_N (TILE + 2 * HALO)   // 1056

struct CombTable { int a[NK], b[NK], c[NK]; };
constexpr CombTable make_combs() {
    CombTable t{};
    int n = 0;
    for (int i = 0; i < KLEN; ++i)
        for (int j = i + 1; j < KLEN; ++j)
            for (int k = j + 1; k < KLEN; ++k) {
                t.a[n] = i; t.b[n] = j; t.c[n] = k; ++n;
            }
    return t;
}
constexpr CombTable COMBS = make_combs();  // lexicographic == itertools.combinations

__global__ __launch_bounds__(256) void rocket_conv(const float* __restrict__ x,
                                                   float* __restrict__ out) {
    __shared__ __align__(16) float lds[LDS_N];

    const int tid  = threadIdx.x;
    const int tile = blockIdx.x;   // 0..3
    const int c    = blockIdx.y;   // 0..15
    const int b    = blockIdx.z;   // 0..15
    const int t0   = tile * TILE;

    // Stage input tile + halo into LDS, zero-padding out-of-range.
    const float* xbc = x + ((size_t)b * CC + c) * TT;
    for (int i = tid; i < LDS_N; i += 256) {
        int g = t0 - HALO + i;
        lds[i] = (g >= 0 && g < TT) ? xbc[g] : 0.0f;
    }
    __syncthreads();

    // Each thread handles 4 consecutive t values.
    const int lt = 4 * tid;
    float4 tap[KLEN];
#pragma unroll
    for (int j = 0; j < KLEN; ++j)
        tap[j] = *(const float4*)&lds[lt + 4 * j];

    float4 s;
    s.x = s.y = s.z = s.w = 0.0f;
#pragma unroll
    for (int j = 0; j < KLEN; ++j) {
        s.x += tap[j].x; s.y += tap[j].y; s.z += tap[j].z; s.w += tap[j].w;
    }

    // Output: flat row order per batch is (c, k): row r = c*NK + k.
    // Base for this (b, c, k=0, t-range); stride between k's is TT floats.
    float4* o = (float4*)out +
                (((size_t)(b * CC + c) * NK) * TT + t0 + lt) / 4;
    const size_t kstr = TT / 4;   // 1024 float4s between consecutive k rows

#pragma unroll
    for (int k = 0; k < NK; ++k) {
        const float4 ta = tap[COMBS.a[k]];
        const float4 tb = tap[COMBS.b[k]];
        const float4 tc = tap[COMBS.c[k]];
        float4 r;
        r.x = 3.0f * (ta.x + tb.x + tc.x) - s.x;
        r.y = 3.0f * (ta.y + tb.y + tc.y) - s.y;
        r.z = 3.0f * (ta.z + tb.z + tc.z) - s.z;
        r.w = 3.0f * (ta.w + tb.w + tc.w) - s.w;
        o[(size_t)k * kstr] = r;
    }
}

extern "C" void kernel_launch(void* const* d_in, const int* in_sizes, int n_in,
                              void* d_out, int out_size, void* d_ws, size_t ws_size,
                              hipStream_t stream) {
    const float* x = (const float*)d_in[0];
    float* out     = (float*)d_out;
    dim3 grid(TT / TILE, CC, BB);   // 4 x 16 x 16 = 1024 blocks
    rocket_conv<<<grid, 256, 0, stream>>>(x, out);
}